// Round 17
// baseline (101.685 us; speedup 1.0000x reference)
//
#include <hip/hip_runtime.h>
#include <math.h>

// CircleLoss, symmetric-triangle bf16-MFMA, 128x64 tiles / ONE phase per block.
//   R15/R16 lesson: the limiter is the serialized stage->bar->MFMA->epilogue
//   phase path. R17: half-width tiles (A 32KB + B 16KB = 48KB -> 3 blocks/CU)
//   so each block is a single phase; 4160 active blocks; same total MFMA/sims.
//   Triangle: block (R,C) active iff C >= 2R (C: 64-col tiles, R: 128-row).
//   C in {2R,2R+1} = diag-type: row partials only, per-element self-exclusion
//   (each ordered pair in the strip counted once via its column-half).
//   C >= 2R+2: row partials AND col partials (sim symmetric).
//   Slots: row = 2C+wc (in [4*RTg,256)), col = 256+2R+wr; rowloss reads
//   exactly the written set. No atomics, deterministic.
//   Numerics: u-form epilogue + DIRECT (P,N) accumulation (no T-P cancel).
// ws (256MB): 2MB featsN + 12.6MB partial[384][B] + 1KB blocksum.

#define DIM 128
#define NSLOT 384
typedef short bf16x8 __attribute__((ext_vector_type(8)));
typedef float f32x4 __attribute__((ext_vector_type(4)));

#if __has_builtin(__builtin_amdgcn_exp2f)
#define EXP2F __builtin_amdgcn_exp2f
#else
#define EXP2F exp2f
#endif

__device__ __forceinline__ unsigned short f2bf(float f) {
    unsigned int b = __float_as_uint(f);
    unsigned int r = (b + 0x7FFFu + ((b >> 16) & 1u)) >> 16;   // RN-even
    return (unsigned short)r;
}
__device__ __forceinline__ unsigned int packPN(float p, float n) {
    return (unsigned int)f2bf(p) | ((unsigned int)f2bf(n) << 16);
}

// ---------------- Kernel 1: normalize + quantize ----------------
__global__ void prep_kernel(const float* __restrict__ feats,
                            unsigned int* __restrict__ featsN, int B) {
    int wave = (blockIdx.x * blockDim.x + threadIdx.x) >> 6;
    int lane = threadIdx.x & 63;
    if (wave >= B) return;
    const float2* rp = (const float2*)(feats + (size_t)wave * DIM);
    float2 v = rp[lane];
    float s = v.x * v.x + v.y * v.y;
#pragma unroll
    for (int off = 32; off; off >>= 1) s += __shfl_xor(s, off);
    float inv = rsqrtf(s);
    featsN[(size_t)wave * 64 + lane] =
        (unsigned int)f2bf(v.x * inv) | ((unsigned int)f2bf(v.y * inv) << 16);
}

// ---------------- Kernel 2: single-phase 128x64 tile blocks ----------------
// grid (128 C-tiles, 64 R-tiles); active iff C >= 2R. 4 waves: 2 wr x 2 wc,
// wave = 64 rows x 32 cols.
__global__ __launch_bounds__(256, 2) void circle_main_kernel(
    const unsigned short* __restrict__ featsN, const int* __restrict__ labels,
    unsigned int* __restrict__ partial, int B) {
    const int C = blockIdx.x;
    const int R = blockIdx.y;
    if (C < 2 * R) return;
    const bool diagType = ((C >> 1) == R);

    __shared__ unsigned char smem[49152] __attribute__((aligned(16)));
    unsigned char* Al = smem;                     // 32KB: A 128 rows
    unsigned char* Bl = smem + 32768;             // 16KB: B 64 rows
    unsigned int* tbuf = (unsigned int*)smem;     // 17408B, aliases dead Al

    const int tid = threadIdx.x;
    const int lane = tid & 63;
    const int wv = tid >> 6;
    const int wr = wv >> 1, wc = wv & 1;
    const int lg = lane >> 4;
    const int l15 = lane & 15;
    const int rowbase = R * 128 + wr * 64;

    // ---- stage A (128 rows) + B (64 rows), 4-bit XOR swizzle ----
    {
        const int r0 = tid >> 4, cc = tid & 15;
        const int swz = ((cc ^ r0) << 4);         // row&15 == r0 for all its
#pragma unroll
        for (int it = 0; it < 8; ++it) {
            int row = it * 16 + r0;
            int4 va = *(const int4*)(featsN + (size_t)(R * 128 + row) * DIM + cc * 8);
            *(int4*)(Al + row * 256 + swz) = va;
        }
#pragma unroll
        for (int it = 0; it < 4; ++it) {
            int row = it * 16 + r0;
            int4 vb = *(const int4*)(featsN + (size_t)(C * 64 + row) * DIM + cc * 8);
            *(int4*)(Bl + row * 256 + swz) = vb;
        }
    }

    int lr[4][4];
#pragma unroll
    for (int m = 0; m < 4; ++m)
#pragma unroll
        for (int r = 0; r < 4; ++r) lr[m][r] = labels[rowbase + m * 16 + lg * 4 + r];

    __syncthreads();

    // ---- MFMA: 32 per wave (4m x 2n x 4k) ----
    f32x4 acc[4][2];
#pragma unroll
    for (int m = 0; m < 4; ++m)
#pragma unroll
        for (int n = 0; n < 2; ++n) acc[m][n] = (f32x4){0.f, 0.f, 0.f, 0.f};
#pragma unroll
    for (int kk = 0; kk < 4; ++kk) {
        bf16x8 af[4], bfr[2];
#pragma unroll
        for (int m = 0; m < 4; ++m) {
            int row = wr * 64 + m * 16 + l15;
            af[m] = __builtin_bit_cast(bf16x8,
                *(const int4*)(Al + row * 256 + (((kk * 4 + lg) ^ l15) << 4)));
        }
#pragma unroll
        for (int n = 0; n < 2; ++n) {
            int row = wc * 32 + n * 16 + l15;
            bfr[n] = __builtin_bit_cast(bf16x8,
                *(const int4*)(Bl + row * 256 + (((kk * 4 + lg) ^ l15) << 4)));
        }
#pragma unroll
        for (int m = 0; m < 4; ++m)
#pragma unroll
            for (int n = 0; n < 2; ++n)
                acc[m][n] = __builtin_amdgcn_mfma_f32_16x16x32_bf16(
                    af[m], bfr[n], acc[m][n], 0, 0, 0);
    }

    // ---- epilogue: u-form, DIRECT (P, N) accumulation ----
    const int colbase = C * 64 + wc * 32;
    const float S2 = 46.166241308446828f;   // 32*log2(e)
    const float C2 = -23.083120654223414f;  // -0.5*S2

    int lc[2];
#pragma unroll
    for (int n = 0; n < 2; ++n) lc[n] = labels[colbase + n * 16 + l15];

    float rP[4][4], rN[4][4];

    if (diagType) {
#pragma unroll
        for (int m = 0; m < 4; ++m) {
#pragma unroll
            for (int r = 0; r < 4; ++r) {
                const int grow = rowbase + m * 16 + lg * 4 + r;
                const int lrow = lr[m][r];
                float psum = 0.f, nsum = 0.f;
#pragma unroll
                for (int n = 0; n < 2; ++n) {
                    float sim = acc[m][n][r];
                    bool same = (lrow == lc[n]);
                    float u = same ? (1.25f - sim) : (sim + 0.25f);
                    float e2 = fmaxf(u, 0.f) * fmaf(S2, u, C2);
                    float v = EXP2F(e2);
                    bool self = (grow == colbase + n * 16 + l15);
                    float pv = (same && !self) ? v : 0.f;
                    float nv = same ? 0.f : v;    // self is same -> excluded
                    psum += pv; nsum += nv;
                }
                rP[m][r] = psum; rN[m][r] = nsum;
            }
        }
    } else {
        float cP[2] = {0.f, 0.f}, cN[2] = {0.f, 0.f};
#pragma unroll
        for (int m = 0; m < 4; ++m) {
#pragma unroll
            for (int r = 0; r < 4; ++r) {
                const int lrow = lr[m][r];
                float psum = 0.f, nsum = 0.f;
#pragma unroll
                for (int n = 0; n < 2; ++n) {
                    float sim = acc[m][n][r];
                    bool same = (lrow == lc[n]);
                    float u = same ? (1.25f - sim) : (sim + 0.25f);
                    float e2 = fmaxf(u, 0.f) * fmaf(S2, u, C2);
                    float v = EXP2F(e2);
                    float pv = same ? v : 0.f;
                    float nv = v - pv;            // exact: pv is v or 0
                    psum += pv; nsum += nv;
                    cP[n] += pv; cN[n] += nv;
                }
                rP[m][r] = psum; rN[m][r] = nsum;
            }
        }
        // col partials: shuffle reduce over lane groups, slot = 256 + 2R + wr
#pragma unroll
        for (int n = 0; n < 2; ++n) {
            float p = cP[n], n_ = cN[n];
            p += __shfl_xor(p, 16); p += __shfl_xor(p, 32);
            n_ += __shfl_xor(n_, 16); n_ += __shfl_xor(n_, 32);
            if (lg == 0) {
                int gcol = colbase + n * 16 + l15;
                partial[(size_t)(256 + R * 2 + wr) * B + gcol] = packPN(p, n_);
            }
        }
    }

    // ---- row partials: transpose-reduce (tbuf aliases Al), slot = 2C + wc ----
    __syncthreads();   // all Al/Bl fragment reads complete before reuse
    {
        unsigned int* T = tbuf + wv * 64 * 17;
#pragma unroll
        for (int m = 0; m < 4; ++m)
#pragma unroll
            for (int r = 0; r < 4; ++r)
                T[(m * 16 + lg * 4 + r) * 17 + l15] = packPN(rP[m][r], rN[m][r]);
    }
    __syncthreads();
    {
        const unsigned int* T = tbuf + wv * 64 * 17 + lane * 17;
        float p = 0.f, n_ = 0.f;
#pragma unroll
        for (int c = 0; c < 16; ++c) {
            unsigned int v = T[c];
            p += __uint_as_float(v << 16);
            n_ += __uint_as_float(v & 0xFFFF0000u);
        }
        int grow = R * 128 + wr * 64 + lane;
        partial[(size_t)(C * 2 + wc) * B + grow] = packPN(p, n_);
    }
}

// ---------------- Kernel 3: per-row log1p(p*n), wave sums ----------------
// Row g: row slots [4*RTg, 256) + col slots [256, 256+kmax).
__global__ void rowloss_kernel(const unsigned int* __restrict__ partial,
                               double* __restrict__ blocksum, int B) {
    int row = blockIdx.x * 64 + threadIdx.x;
    int RTg = row >> 7;
    int Cg = row >> 6;
    float p = 0.f, n = 0.f;
    for (int c = 4 * RTg; c < 256; ++c) {
        unsigned int v = partial[(size_t)c * B + row];
        p += __uint_as_float(v << 16);
        n += __uint_as_float(v & 0xFFFF0000u);
    }
    int kmax = (Cg >= 2) ? ((((Cg - 2) >> 1) + 1) << 1) : 0;
    for (int c = 256; c < 256 + kmax; ++c) {
        unsigned int v = partial[(size_t)c * B + row];
        p += __uint_as_float(v << 16);
        n += __uint_as_float(v & 0xFFFF0000u);
    }
    double l = log1p((double)p * (double)n);
#pragma unroll
    for (int off = 32; off; off >>= 1) l += __shfl_xor(l, off);
    if (threadIdx.x == 0) blocksum[blockIdx.x] = l;
}

__global__ void final_kernel(const double* __restrict__ blocksum,
                             float* __restrict__ out, int nblk, int B) {
    __shared__ double sdata[128];
    int tid = threadIdx.x;
    sdata[tid] = (tid < nblk) ? blocksum[tid] : 0.0;
    __syncthreads();
    for (int s = 64; s; s >>= 1) {
        if (tid < s) sdata[tid] += sdata[tid + s];
        __syncthreads();
    }
    if (tid == 0) out[0] = (float)(sdata[0] / (double)B);
}

extern "C" void kernel_launch(void* const* d_in, const int* in_sizes, int n_in,
                              void* d_out, int out_size, void* d_ws, size_t ws_size,
                              hipStream_t stream) {
    const float* feats = (const float*)d_in[0];
    const int* labels = (const int*)d_in[1];
    float* out = (float*)d_out;
    int B = in_sizes[1];  // 8192

    // ws: featsN bf16 [B][128] (2MB) | partial u32 [384][B] (12.6MB) | blocksum
    unsigned int* featsN = (unsigned int*)d_ws;
    size_t off1 = ((size_t)B * DIM * 2 + 255) & ~(size_t)255;
    unsigned int* partial = (unsigned int*)((char*)d_ws + off1);
    size_t off2 = off1 + (((size_t)B * NSLOT * sizeof(unsigned int) + 255) & ~(size_t)255);
    double* blocksum = (double*)((char*)d_ws + off2);

    prep_kernel<<<B / 4, 256, 0, stream>>>(feats, featsN, B);

    dim3 grid(128, 64);   // (C, R); blocks with C < 2R exit immediately
    circle_main_kernel<<<grid, 256, 0, stream>>>((const unsigned short*)featsN,
                                                 labels, partial, B);

    int nblk = B / 64;    // 128
    rowloss_kernel<<<nblk, 64, 0, stream>>>(partial, blocksum, B);
    final_kernel<<<1, 128, 0, stream>>>(blocksum, out, nblk, B);
}

// Round 18
// 42.279 us; speedup vs baseline: 2.4051x; 2.4051x over previous
//
#include <hip/hip_runtime.h>
#include <math.h>

// CircleLoss, symmetric-triangle bf16-MFMA (R14-validated main) + pk-f32
// epilogue accumulators + parallel rowloss.
//   R15/R16/R17 lesson: phase structure is not the lever (main ~33us across
//   all three). R18: (1) float2-packed (p,n) accumulators -> v_pk_add_f32,
//   -2 VALU ops/sim; (2) rowloss re-gridded 128x256 with 4-way slot split
//   (R17's 64-thread rowloss was 63us at 1% occupancy).
//   Triangle: tile pairs (RT<=CT); u-form epilogue; DIRECT (P,N) accumulation
//   (no T-P cancellation); transposed partial[slot][row] packed bf16; slots
//   col=2RT+wr, row=2CT+wc cover 0..127 once per row. No atomics.
// ws (256MB avail): 2MB featsN + 4MB partial[128][B] + 1KB blocksum.

#define DIM 128
typedef short bf16x8 __attribute__((ext_vector_type(8)));
typedef float f32x4 __attribute__((ext_vector_type(4)));
typedef float f32x2 __attribute__((ext_vector_type(2)));

#if __has_builtin(__builtin_amdgcn_exp2f)
#define EXP2F __builtin_amdgcn_exp2f
#else
#define EXP2F exp2f
#endif

__device__ __forceinline__ unsigned short f2bf(float f) {
    unsigned int b = __float_as_uint(f);
    unsigned int r = (b + 0x7FFFu + ((b >> 16) & 1u)) >> 16;   // RN-even
    return (unsigned short)r;
}
__device__ __forceinline__ unsigned int packPN(float p, float n) {
    return (unsigned int)f2bf(p) | ((unsigned int)f2bf(n) << 16);
}

// ---------------- Kernel 1: normalize + quantize ----------------
__global__ void prep_kernel(const float* __restrict__ feats,
                            unsigned int* __restrict__ featsN, int B) {
    int wave = (blockIdx.x * blockDim.x + threadIdx.x) >> 6;
    int lane = threadIdx.x & 63;
    if (wave >= B) return;
    const float2* rp = (const float2*)(feats + (size_t)wave * DIM);
    float2 v = rp[lane];
    float s = v.x * v.x + v.y * v.y;
#pragma unroll
    for (int off = 32; off; off >>= 1) s += __shfl_xor(s, off);
    float inv = rsqrtf(s);
    featsN[(size_t)wave * 64 + lane] =
        (unsigned int)f2bf(v.x * inv) | ((unsigned int)f2bf(v.y * inv) << 16);
}

// ---------------- Kernel 2: triangular fused MFMA + masked exp ----------------
// 2080 blocks = tile pairs (RT,CT), RT<=CT. 4 waves in 2x2 of 64x64.
__global__ __launch_bounds__(256, 2) void circle_main_kernel(
    const unsigned short* __restrict__ featsN, const int* __restrict__ labels,
    unsigned int* __restrict__ partial, int B) {
    __shared__ unsigned char smem[65536] __attribute__((aligned(16)));
    unsigned char* Al = smem;
    unsigned char* Bl = smem + 32768;
    unsigned int* tbuf = (unsigned int*)smem;   // transpose scratch, aliases tiles

    // ---- unrank bid -> (RT, CT), RT <= CT ----
    int bid = blockIdx.x;
    int RT = (int)((129.0 - sqrt(16641.0 - 8.0 * (double)bid)) * 0.5);
    RT = RT < 0 ? 0 : (RT > 63 ? 63 : RT);
    while (64 * RT - (RT * (RT - 1)) / 2 > bid) --RT;
    while (64 * (RT + 1) - ((RT + 1) * RT) / 2 <= bid) ++RT;
    const int CT = RT + (bid - (64 * RT - (RT * (RT - 1)) / 2));
    const bool diag = (RT == CT);

    const int tid = threadIdx.x;
    const int lane = tid & 63;
    const int wv = tid >> 6;
    const int wr = wv >> 1, wc = wv & 1;
    const int lg = lane >> 4;
    const int l15 = lane & 15;

    // ---- stage A (RT rows) and B (CT rows), 4-bit XOR swizzle ----
    {
        const int r0 = tid >> 4, c = tid & 15;
#pragma unroll
        for (int it = 0; it < 8; ++it) {
            int row = it * 16 + r0;
            int swz = ((c ^ (row & 15)) << 4);
            int4 va = *(const int4*)(featsN + (size_t)(RT * 128 + row) * DIM + c * 8);
            *(int4*)(Al + row * 256 + swz) = va;
            int4 vb = *(const int4*)(featsN + (size_t)(CT * 128 + row) * DIM + c * 8);
            *(int4*)(Bl + row * 256 + swz) = vb;
        }
    }
    __syncthreads();

    // ---- MFMA: 64 per wave (4m x 4n x 4k) ----
    f32x4 acc[4][4];
#pragma unroll
    for (int m = 0; m < 4; ++m)
#pragma unroll
        for (int n = 0; n < 4; ++n) acc[m][n] = (f32x4){0.f, 0.f, 0.f, 0.f};
#pragma unroll
    for (int kk = 0; kk < 4; ++kk) {
        bf16x8 af[4], bfr[4];
#pragma unroll
        for (int m = 0; m < 4; ++m) {
            int row = wr * 64 + m * 16 + l15;
            af[m] = __builtin_bit_cast(bf16x8,
                *(const int4*)(Al + row * 256 + (((kk * 4 + lg) ^ (row & 15)) << 4)));
        }
#pragma unroll
        for (int n = 0; n < 4; ++n) {
            int row = wc * 64 + n * 16 + l15;
            bfr[n] = __builtin_bit_cast(bf16x8,
                *(const int4*)(Bl + row * 256 + (((kk * 4 + lg) ^ (row & 15)) << 4)));
        }
#pragma unroll
        for (int m = 0; m < 4; ++m)
#pragma unroll
            for (int n = 0; n < 4; ++n)
                acc[m][n] = __builtin_amdgcn_mfma_f32_16x16x32_bf16(
                    af[m], bfr[n], acc[m][n], 0, 0, 0);
    }

    // ---- epilogue: u-form, packed (P,N) accumulation ----
    const int rowbase = RT * 128 + wr * 64;
    const int colbase = CT * 128 + wc * 64;
    const float S2 = 46.166241308446828f;   // 32*log2(e)
    const float C2 = -23.083120654223414f;  // -0.5*S2

    int lc[4], lr[4][4];
#pragma unroll
    for (int n = 0; n < 4; ++n) lc[n] = labels[colbase + n * 16 + l15];
#pragma unroll
    for (int m = 0; m < 4; ++m)
#pragma unroll
        for (int r = 0; r < 4; ++r) lr[m][r] = labels[rowbase + m * 16 + lg * 4 + r];

    f32x2 rPN[4][4];
    f32x2 cPN[4] = {(f32x2){0.f, 0.f}, (f32x2){0.f, 0.f},
                    (f32x2){0.f, 0.f}, (f32x2){0.f, 0.f}};

    if (diag) {
#pragma unroll
        for (int m = 0; m < 4; ++m) {
#pragma unroll
            for (int r = 0; r < 4; ++r) {
                const int grow = rowbase + m * 16 + lg * 4 + r;
                const int lrow = lr[m][r];
                f32x2 s_ = (f32x2){0.f, 0.f};
#pragma unroll
                for (int n = 0; n < 4; ++n) {
                    float sim = acc[m][n][r];
                    bool same = (lrow == lc[n]);
                    float u = same ? (1.25f - sim) : (sim + 0.25f);
                    float e2 = fmaxf(u, 0.f) * fmaf(S2, u, C2);
                    float v = EXP2F(e2);
                    bool self = (grow == colbase + n * 16 + l15);
                    v = self ? 0.f : v;             // self excluded everywhere
                    float pv = same ? v : 0.f;
                    s_ += (f32x2){pv, v - pv};      // {P, N} packed add
                }
                rPN[m][r] = s_;
            }
        }
    } else {
#pragma unroll
        for (int m = 0; m < 4; ++m) {
#pragma unroll
            for (int r = 0; r < 4; ++r) {
                const int lrow = lr[m][r];
                f32x2 s_ = (f32x2){0.f, 0.f};
#pragma unroll
                for (int n = 0; n < 4; ++n) {
                    float sim = acc[m][n][r];
                    bool same = (lrow == lc[n]);
                    float u = same ? (1.25f - sim) : (sim + 0.25f);
                    float e2 = fmaxf(u, 0.f) * fmaf(S2, u, C2);
                    float v = EXP2F(e2);
                    float pv = same ? v : 0.f;
                    f32x2 w = (f32x2){pv, v - pv};  // exact: pv is v or 0
                    s_ += w;
                    cPN[n] += w;
                }
                rPN[m][r] = s_;
            }
        }
    }

    // ---- col partials (off-diag only): shuffle reduce over lane groups ----
    if (!diag) {
#pragma unroll
        for (int n = 0; n < 4; ++n) {
            float p = cPN[n].x, n_ = cPN[n].y;
            p += __shfl_xor(p, 16); p += __shfl_xor(p, 32);
            n_ += __shfl_xor(n_, 16); n_ += __shfl_xor(n_, 32);
            if (lg == 0) {
                int gcol = colbase + n * 16 + l15;
                partial[(size_t)(RT * 2 + wr) * B + gcol] = packPN(p, n_);
            }
        }
    }

    // ---- row partials: LDS transpose reduce (aliased over dead tiles) ----
    __syncthreads();   // all LDS tile reads (MFMA fragments) complete
    {
        unsigned int* T = tbuf + wv * 64 * 17;
#pragma unroll
        for (int m = 0; m < 4; ++m)
#pragma unroll
            for (int r = 0; r < 4; ++r)
                T[(m * 16 + lg * 4 + r) * 17 + l15] = packPN(rPN[m][r].x, rPN[m][r].y);
    }
    __syncthreads();
    {
        const unsigned int* T = tbuf + wv * 64 * 17 + lane * 17;
        float p = 0.f, n_ = 0.f;
#pragma unroll
        for (int c = 0; c < 16; ++c) {
            unsigned int v = T[c];
            p += __uint_as_float(v << 16);
            n_ += __uint_as_float(v & 0xFFFF0000u);
        }
        int grow = RT * 128 + wr * 64 + lane;
        partial[(size_t)(CT * 2 + wc) * B + grow] = packPN(p, n_);
    }
}

// ---------------- Kernel 3: per-row log1p(p*n), parallel over slots ----------------
// 128 blocks x 256 threads: thread (row-in-64, quarter) sums 32 slots; LDS
// combine; wave 0 does log1p + 64-lane reduce -> blocksum.
__global__ void rowloss_kernel(const unsigned int* __restrict__ partial,
                               double* __restrict__ blocksum, int B) {
    __shared__ float2 sdata[64][4];
    int tid = threadIdx.x;
    int r6 = tid & 63, q = tid >> 6;
    int row = blockIdx.x * 64 + r6;
    float p = 0.f, n = 0.f;
#pragma unroll
    for (int c = q * 32; c < q * 32 + 32; ++c) {
        unsigned int v = partial[(size_t)c * B + row];
        p += __uint_as_float(v << 16);
        n += __uint_as_float(v & 0xFFFF0000u);
    }
    sdata[r6][q] = make_float2(p, n);
    __syncthreads();
    if (q == 0) {
        float2 a0 = sdata[r6][0], a1 = sdata[r6][1];
        float2 a2 = sdata[r6][2], a3 = sdata[r6][3];
        double pf = (double)(a0.x + a1.x + a2.x + a3.x);
        double nf = (double)(a0.y + a1.y + a2.y + a3.y);
        double l = log1p(pf * nf);
#pragma unroll
        for (int off = 32; off; off >>= 1) l += __shfl_xor(l, off);
        if (r6 == 0) blocksum[blockIdx.x] = l;
    }
}

__global__ void final_kernel(const double* __restrict__ blocksum,
                             float* __restrict__ out, int nblk, int B) {
    __shared__ double sdata[128];
    int tid = threadIdx.x;
    sdata[tid] = (tid < nblk) ? blocksum[tid] : 0.0;
    __syncthreads();
    for (int s = 64; s; s >>= 1) {
        if (tid < s) sdata[tid] += sdata[tid + s];
        __syncthreads();
    }
    if (tid == 0) out[0] = (float)(sdata[0] / (double)B);
}

extern "C" void kernel_launch(void* const* d_in, const int* in_sizes, int n_in,
                              void* d_out, int out_size, void* d_ws, size_t ws_size,
                              hipStream_t stream) {
    const float* feats = (const float*)d_in[0];
    const int* labels = (const int*)d_in[1];
    float* out = (float*)d_out;
    int B = in_sizes[1];  // 8192

    // ws: featsN bf16 [B][128] (2MB) | partial u32 [128][B] (4MB) | blocksum (1KB)
    unsigned int* featsN = (unsigned int*)d_ws;
    size_t off1 = ((size_t)B * DIM * 2 + 255) & ~(size_t)255;
    unsigned int* partial = (unsigned int*)((char*)d_ws + off1);
    size_t off2 = off1 + (((size_t)B * 128 * sizeof(unsigned int) + 255) & ~(size_t)255);
    double* blocksum = (double*)((char*)d_ws + off2);

    prep_kernel<<<B / 4, 256, 0, stream>>>(feats, featsN, B);

    int ntiles = B / 128;                      // 64
    int nblocks = ntiles * (ntiles + 1) / 2;   // 2080
    circle_main_kernel<<<nblocks, 256, 0, stream>>>((const unsigned short*)featsN,
                                                    labels, partial, B);

    int nblk = B / 64;  // 128
    rowloss_kernel<<<nblk, 256, 0, stream>>>(partial, blocksum, B);
    final_kernel<<<1, 128, 0, stream>>>(blocksum, out, nblk, B);
}